// Round 5
// baseline (286.310 us; speedup 1.0000x reference)
//
#include <hip/hip_runtime.h>

// VQ-VAE VectorQuantizer: fp16 single-term MFMA distance + INLINE exact fp32
// re-rank. z: (32,64,64,64) NCHW fp32; codebook: (1024,64) fp32.
// d_out: [0]=loss, [1..]=z_q (NCHW).
//
// R13 (from R12 post-mortem): vq_fix still cost ~40us (launch + ramp + per-
// wave cold scans) for ~1.2 flagged queries per block. Fold the exact re-rank
// INTO vq_main, between the merge and the z_q epilogue:
//  - flags stay in LDS (flist_s); no flag arrays, no loss_adj atomics, no
//    z_q overwrites (idx_s patched before the write).
//  - per flag: stage z[ql] (64 f32, L3-hot) to LDS; 256 threads score 4
//    codes each in exact fp32 (same sum((z-c)^2) as the passing vq_fix;
//    ascending-j first-min tie-break); block-reduce; patch idx_s + contrib.
//  - loss: contrib_s[128] per block -> loss_part[blockIdx]; LAST main block
//    (done_cnt, threadfence pattern proven in vq_fix) reduces 1024 partials
//    and writes out[0]. vq_fix kernel deleted.
// vq_main hot loop / vq_prep unchanged (R10-proven: no-spill (256,3), fp16
// single-term MFMA, LDS dbuf one-barrier-per-chunk, deferred tracking banks).

#define CB_N   1024
#define KDIM   64
#define HWD    4096
#define CHW    (KDIM * HWD)
#define NQ     131072
#define TOTALF 8388608.0f
#define TAU    0.02f
#define CHUNK  128            // codes per LDS chunk
#define NCHUNK (CB_N / CHUNK)

typedef __attribute__((ext_vector_type(8))) _Float16 half8;
typedef __attribute__((ext_vector_type(4))) float    f32x4;

// async 16B/lane global->LDS copy (wave-uniform contiguous; m97 pattern)
__device__ __forceinline__ void gload_lds16(const void* g, void* l) {
    __builtin_amdgcn_global_load_lds(
        (const __attribute__((address_space(1))) unsigned int*)g,
        (__attribute__((address_space(3))) unsigned int*)l,
        16, 0, 0);
}

// ---------- ws layout (byte offsets) ----------
// 8: done_cnt
// 128:  loss_part f32[1024]
// 4224: norms     f32[1024]
// 8320: cbh_sw    u16[1024*64]   (fp16, rotate-swizzled row segments)

// ---------------- prep: fp16 convert, swizzled rows, norms, counter --------
__global__ void vq_prep(const float* __restrict__ cb,
                        float* __restrict__ norms,
                        unsigned short* __restrict__ cbh,
                        int* __restrict__ done_cnt) {
    const int tid = blockIdx.x * 256 + threadIdx.x;
    if (tid == 0) *done_cnt = 0;
    const int j  = tid >> 2;
    const int s2 = tid & 3;

    const float4* r4 = (const float4*)(cb + (size_t)j * KDIM);
    float s_norm = 0.0f;
    #pragma unroll
    for (int seg8 = 0; seg8 < 2; ++seg8) {
        const int s = s2 * 2 + seg8;
        float4 v0 = r4[s * 2 + 0];
        float4 v1 = r4[s * 2 + 1];
        float e[8] = {v0.x, v0.y, v0.z, v0.w, v1.x, v1.y, v1.z, v1.w};
        unsigned hh[4];
        #pragma unroll
        for (int c = 0; c < 8; ++c) {
            float x = e[c];
            s_norm = fmaf(x, x, s_norm);
            union { _Float16 h; unsigned short u; } cv;
            cv.h = (_Float16)x;                       // RNE fp16
            if ((c & 1) == 0) hh[c >> 1] = cv.u;
            else              hh[c >> 1] |= ((unsigned)cv.u) << 16;
        }
        const int p = (s + j) & 7;                    // bank-deconflict rotate
        *(uint4*)(cbh + (size_t)j * KDIM + p * 8) = make_uint4(hh[0], hh[1], hh[2], hh[3]);
    }
    s_norm += __shfl_xor(s_norm, 1, 64);
    s_norm += __shfl_xor(s_norm, 2, 64);
    if (s2 == 0) norms[j] = s_norm;
}

// ---------------- main ------------------------------------------------------
__global__ __launch_bounds__(256, 3) void vq_main(
        const float* __restrict__ z,
        const float* __restrict__ cb,
        const unsigned short* __restrict__ cbh,
        const float* __restrict__ norms,
        float* __restrict__ out,
        float* __restrict__ loss_part,
        int* __restrict__ done_cnt) {
    __shared__ float          norms_s[CB_N];             // 4 KB
    __shared__ unsigned short bh_s[2][CHUNK * KDIM];     // 2 x 16 KB (dbuf)
    __shared__ float          zn_s[128];
    __shared__ int            idx_s[128];
    __shared__ float          contrib_s[128];            // per-query loss term
    __shared__ float          zf_s[64];                  // staged z for re-rank
    __shared__ short          flist_s[128];
    __shared__ int            nflag_s;
    __shared__ float          rb_s[4];
    __shared__ int            rj_s[4];
    __shared__ float          wsum_s[2];
    __shared__ int            last_s;

    const int tid  = threadIdx.x;
    const int w    = tid >> 6;
    const int lane = tid & 63;
    const int quad = lane >> 4;
    const int l16  = lane & 15;
    const int qb   = blockIdx.x * 128;     // block's 128 queries (same batch b)
    const int b    = qb >> 12;
    const int hw0  = qb & 4095;
    const int ch0  = blockIdx.x & (NCHUNK - 1);   // de-phase chunk start

    if (tid == 0) nflag_s = 0;

    // ---- issue stage of chunk 0 FIRST (flies under the z-read prologue)
    {
        const char* gh = (const char*)cbh + (size_t)(ch0 & (NCHUNK - 1)) * (CHUNK * KDIM * 2);
        char* lh = (char*)(&bh_s[0][0]);
        #pragma unroll
        for (int i = 0; i < 4; ++i) {
            const int off = (w * 4 + i) * 1024 + lane * 16;
            gload_lds16(gh + off, lh + off);
        }
    }

    // ---- stage all code norms into LDS
    *(float4*)(norms_s + tid * 4) = *(const float4*)(norms + tid * 4);

    // ---- stage A-frags: wave w owns queries [32w, 32w+32); 2 tiles of 16.
    const float* zbase = z + (size_t)b * CHW + hw0 + 32 * w;
    half8 ah[2][2];
    float znp[2] = {0.f, 0.f};
    #pragma unroll
    for (int t = 0; t < 2; ++t)
        #pragma unroll
        for (int ks = 0; ks < 2; ++ks)
            #pragma unroll
            for (int j = 0; j < 8; ++j) {
                float v = zbase[(size_t)(ks * 32 + quad * 8 + j) * HWD + t * 16 + l16];
                znp[t] = fmaf(v, v, znp[t]);
                ah[t][ks][j] = (_Float16)(-2.0f * v);   // RNE fp16
            }
    #pragma unroll
    for (int t = 0; t < 2; ++t) {
        znp[t] += __shfl_xor(znp[t], 16, 64);
        znp[t] += __shfl_xor(znp[t], 32, 64);
    }
    if (lane < 16) {
        zn_s[32 * w + lane]      = znp[0];
        zn_s[32 * w + 16 + lane] = znp[1];
    }

    float m1[2][4], m2[2][4];
    int   i1[2][4];
    #pragma unroll
    for (int t = 0; t < 2; ++t)
        #pragma unroll
        for (int r = 0; r < 4; ++r) { m1[t][r] = 3.4e38f; m2[t][r] = 3.4e38f; i1[t][r] = 0; }

    // loop-invariant swizzled segment offsets (ks=0 / ks=1)
    const int p0 = ((quad + l16) & 7) * 8;
    const int p1 = ((4 + quad + l16) & 7) * 8;

    f32x4 bank[2][2];               // [tile-parity][t] -- deferred tracking
    bank[0][0] = bank[0][1] = (f32x4){0.f, 0.f, 0.f, 0.f};
    bank[1][0] = bank[1][1] = (f32x4){0.f, 0.f, 0.f, 0.f};
    int prevCode = 0;

    __syncthreads();                // chunk 0 staged + norms_s/zn_s visible
    int cur = 0;

    for (int cc = 0; cc < NCHUNK; ++cc) {
        // ---- issue next chunk's stage into the OTHER buffer (overlaps compute)
        if (cc + 1 < NCHUNK) {
            const int chn = (cc + 1 + ch0) & (NCHUNK - 1);
            const char* gh = (const char*)cbh + (size_t)chn * (CHUNK * KDIM * 2);
            char* lh = (char*)(&bh_s[cur ^ 1][0]);
            #pragma unroll
            for (int i = 0; i < 4; ++i) {
                const int off = (w * 4 + i) * 1024 + lane * 16;
                gload_lds16(gh + off, lh + off);
            }
        }

        const int ch = (cc + ch0) & (NCHUNK - 1);
        #pragma unroll
        for (int t8 = 0; t8 < 8; ++t8) {
            const int crow = t8 * 16 + l16;            // chunk-local code row
            const float nv = norms_s[ch * CHUNK + crow];
            const half8 bh0 = *(const half8*)(&bh_s[cur][crow * KDIM + p0]);
            const half8 bh1 = *(const half8*)(&bh_s[cur][crow * KDIM + p1]);
            const int code = ch * CHUNK + crow;
            const int bk = t8 & 1, pv = bk ^ 1;

            // track the DEFERRED tile (previous t8) held in bank[pv];
            // independent of bank[bk]'s MFMAs below -> overlaps them
            if (cc + t8 > 0) {
                #pragma unroll
                for (int t = 0; t < 2; ++t)
                    #pragma unroll
                    for (int r = 0; r < 4; ++r) {
                        float d = bank[pv][t][r];
                        bool cnd = d < m1[t][r];
                        m2[t][r] = __builtin_amdgcn_fmed3f(d, m1[t][r], m2[t][r]);
                        m1[t][r] = fminf(m1[t][r], d);
                        i1[t][r] = cnd ? prevCode : i1[t][r];
                    }
            }

            #pragma unroll
            for (int t = 0; t < 2; ++t) {
                f32x4 acc = {nv, nv, nv, nv};
                acc = __builtin_amdgcn_mfma_f32_16x16x32_f16(ah[t][0], bh0, acc, 0, 0, 0);
                acc = __builtin_amdgcn_mfma_f32_16x16x32_f16(ah[t][1], bh1, acc, 0, 0, 0);
                bank[bk][t] = acc;
            }
            prevCode = code;
        }

        __syncthreads();   // implicit vmcnt(0): next buffer landed; cur reads done
        cur ^= 1;
    }
    // final deferred tile (last t8=7 wrote bank[1])
    {
        #pragma unroll
        for (int t = 0; t < 2; ++t)
            #pragma unroll
            for (int r = 0; r < 4; ++r) {
                float d = bank[1][t][r];
                bool cnd = d < m1[t][r];
                m2[t][r] = __builtin_amdgcn_fmed3f(d, m1[t][r], m2[t][r]);
                m1[t][r] = fminf(m1[t][r], d);
                i1[t][r] = cnd ? prevCode : i1[t][r];
            }
    }

    // ---- merge across 16 lanes (code residues), first-index ties
    #pragma unroll
    for (int s = 1; s < 16; s <<= 1)
        #pragma unroll
        for (int t = 0; t < 2; ++t)
            #pragma unroll
            for (int r = 0; r < 4; ++r) {
                float o1 = __shfl_xor(m1[t][r], s, 64);
                int   oi = __shfl_xor(i1[t][r], s, 64);
                float o2 = __shfl_xor(m2[t][r], s, 64);
                m2[t][r] = __builtin_amdgcn_fmed3f(m1[t][r], o1, fminf(m2[t][r], o2));
                if (o1 < m1[t][r] || (o1 == m1[t][r] && oi < i1[t][r])) {
                    m1[t][r] = o1; i1[t][r] = oi;
                }
            }

    // ---- owners (l16==0): publish idx, contrib, flags (to LDS)
    if (l16 == 0) {
        #pragma unroll
        for (int t = 0; t < 2; ++t)
            #pragma unroll
            for (int r = 0; r < 4; ++r) {
                const int ql = 32 * w + t * 16 + quad * 4 + r;
                idx_s[ql]     = i1[t][r];
                contrib_s[ql] = m1[t][r] + zn_s[ql];
                if (m2[t][r] - m1[t][r] < TAU) {
                    int pos = atomicAdd(&nflag_s, 1);
                    flist_s[pos] = (short)ql;
                }
            }
    }
    __syncthreads();                   // idx_s/contrib_s/flist_s visible

    // ---- inline exact fp32 re-rank for flagged queries (block-uniform loop)
    const int nf = nflag_s;
    for (int fi = 0; fi < nf; ++fi) {
        const int ql = flist_s[fi];
        if (tid < 64)
            zf_s[tid] = z[(size_t)b * CHW + (size_t)tid * HWD + (hw0 + ql)];
        __syncthreads();

        // thread scores codes 4*tid .. 4*tid+3 (exact fp32, ascending j)
        const float4* base = (const float4*)(cb + (size_t)(tid * 4) * KDIM);
        float d0 = 0.f, d1 = 0.f, d2 = 0.f, d3 = 0.f;
        #pragma unroll
        for (int k4 = 0; k4 < 16; ++k4) {
            const float4 zq = *(const float4*)(zf_s + k4 * 4);   // broadcast
            float4 v0 = base[k4], v1 = base[16 + k4], v2 = base[32 + k4], v3 = base[48 + k4];
            float a;
            a = zq.x - v0.x; d0 = fmaf(a, a, d0);
            a = zq.y - v0.y; d0 = fmaf(a, a, d0);
            a = zq.z - v0.z; d0 = fmaf(a, a, d0);
            a = zq.w - v0.w; d0 = fmaf(a, a, d0);
            a = zq.x - v1.x; d1 = fmaf(a, a, d1);
            a = zq.y - v1.y; d1 = fmaf(a, a, d1);
            a = zq.z - v1.z; d1 = fmaf(a, a, d1);
            a = zq.w - v1.w; d1 = fmaf(a, a, d1);
            a = zq.x - v2.x; d2 = fmaf(a, a, d2);
            a = zq.y - v2.y; d2 = fmaf(a, a, d2);
            a = zq.z - v2.z; d2 = fmaf(a, a, d2);
            a = zq.w - v2.w; d2 = fmaf(a, a, d2);
            a = zq.x - v3.x; d3 = fmaf(a, a, d3);
            a = zq.y - v3.y; d3 = fmaf(a, a, d3);
            a = zq.z - v3.z; d3 = fmaf(a, a, d3);
            a = zq.w - v3.w; d3 = fmaf(a, a, d3);
        }
        float bd = d0; int bj = tid * 4;
        if (d1 < bd) { bd = d1; bj = tid * 4 + 1; }
        if (d2 < bd) { bd = d2; bj = tid * 4 + 2; }
        if (d3 < bd) { bd = d3; bj = tid * 4 + 3; }
        #pragma unroll
        for (int s = 1; s < 64; s <<= 1) {
            float ob = __shfl_xor(bd, s, 64);
            int   oj = __shfl_xor(bj, s, 64);
            if (ob < bd || (ob == bd && oj < bj)) { bd = ob; bj = oj; }
        }
        if (lane == 0) { rb_s[w] = bd; rj_s[w] = bj; }
        __syncthreads();
        if (tid == 0) {
            float B = rb_s[0]; int J = rj_s[0];
            #pragma unroll
            for (int wi = 1; wi < 4; ++wi)
                if (rb_s[wi] < B || (rb_s[wi] == B && rj_s[wi] < J)) { B = rb_s[wi]; J = rj_s[wi]; }
            if (J != idx_s[ql]) { idx_s[ql] = J; contrib_s[ql] = B; }
        }
        __syncthreads();               // idx_s patched; zf_s free for next flag
    }

    // ---- block loss partial from contrib_s (waves 0,1 hold tid<128)
    {
        float ls = (tid < 128) ? contrib_s[tid] : 0.0f;
        #pragma unroll
        for (int s = 1; s < 64; s <<= 1) ls += __shfl_xor(ls, s, 64);
        if (lane == 0 && w < 2) wsum_s[w] = ls;
    }
    __syncthreads();
    if (tid == 0) loss_part[blockIdx.x] = wsum_s[0] + wsum_s[1];

    // ---- epilogue: thread -> (query tid&127, channels [32*(tid>>7),+32))
    {
        const int q   = tid & 127;
        const int cs  = (tid >> 7) * 32;
        const int idx = idx_s[q];
        const float4* row = (const float4*)(cb + (size_t)idx * KDIM + cs);
        float* op = out + 1 + (size_t)b * CHW + (size_t)cs * HWD + hw0 + q;
        #pragma unroll
        for (int i4 = 0; i4 < 8; ++i4) {
            float4 v = row[i4];
            op[(size_t)(i4 * 4 + 0) * HWD] = v.x;
            op[(size_t)(i4 * 4 + 1) * HWD] = v.y;
            op[(size_t)(i4 * 4 + 2) * HWD] = v.z;
            op[(size_t)(i4 * 4 + 3) * HWD] = v.w;
        }
    }

    // ---- finalize: last block reduces loss_part[1024] -> out[0]
    __syncthreads();                   // all stores of all waves drained (vmcnt0)
    if (tid == 0) {
        __threadfence();
        last_s = (atomicAdd(done_cnt, 1) == (int)gridDim.x - 1) ? 1 : 0;
    }
    __syncthreads();
    if (last_s) {
        float s = 0.0f;
        for (int i = tid; i < 1024; i += 256) s += loss_part[i];
        #pragma unroll
        for (int sh = 1; sh < 64; sh <<= 1) s += __shfl_xor(s, sh, 64);
        if (lane == 0) rb_s[w] = s;
        __syncthreads();
        if (tid == 0)
            out[0] = 1.25f * (rb_s[0] + rb_s[1] + rb_s[2] + rb_s[3]) / TOTALF;
    }
}

extern "C" void kernel_launch(void* const* d_in, const int* in_sizes, int n_in,
                              void* d_out, int out_size, void* d_ws, size_t ws_size,
                              hipStream_t stream) {
    const float* z  = (const float*)d_in[0];
    const float* cb = (const float*)d_in[1];
    float* out      = (float*)d_out;
    char*  ws       = (char*)d_ws;

    int*            done_cnt  = (int*)(ws + 8);
    float*          loss_part = (float*)(ws + 128);
    float*          norms     = (float*)(ws + 4224);
    unsigned short* cbh       = (unsigned short*)(ws + 8320);

    vq_prep<<<dim3(16), dim3(256), 0, stream>>>(cb, norms, cbh, done_cnt);

    vq_main<<<dim3(NQ / 128), dim3(256), 0, stream>>>(z, cb, cbh, norms, out,
                                                      loss_part, done_cnt);
}

// Round 6
// 161.848 us; speedup vs baseline: 1.7690x; 1.7690x over previous
//
#include <hip/hip_runtime.h>

// VQ-VAE VectorQuantizer: fp16 hi/lo 3-term MFMA distance + exact fp32 fallback.
// z: (32,64,64,64) NCHW fp32; codebook: (1024,64) fp32.
// d_out: [0]=loss, [1..]=z_q (NCHW).
//
// R14 (from R13 post-mortem): R13's inline re-rank regressed main 61->220us
// (uncoalesced per-thread cb scans x ~5000 flags, + per-block threadfence L2
// writebacks). Reverted. The lever is the FLAG COUNT: n scales with TAU,
// TAU scales with main's distance error. fp16 single-term sigma~2e-3 forced
// TAU=0.02 -> n~5000 -> fix ~40us of redundant L2 codebook scans. This round:
//  - fp16 hi/lo split, 3-term MFMA (ah*bh + al*bh + ah*bl): error <~1e-4
//    -> TAU=1e-3 -> n~250 -> R12's proven vq_fix costs ~3-5us.
//  - main is NOT MFMA-bound (MfmaUtil 11%, VALUBusy 45%): 4->12 MFMA/t8 adds
//    ~40cyc against a ~500cyc/t8 envelope; tracking VALU unchanged.
//  - CHUNK 128->64 so the lo plane fits: LDS = 2buf x (8+8)KB + 4KB norms
//    ~= 37KB -> still 3 blocks/CU. dbuf + one barrier per chunk preserved.
//    Rotate-swizzle is mod-8-invariant (16 | CHUNK), p0/p1 unchanged.
// vq_fix: byte-identical to R12's (passing). Loss partials + done_cnt
// finalize unchanged from R12.

#define CB_N   1024
#define KDIM   64
#define HWD    4096
#define CHW    (KDIM * HWD)
#define NQ     131072
#define TOTALF 8388608.0f
#define TAU    1.0e-3f
#define FCAP   16384
#define CHUNK  64             // codes per LDS chunk
#define NCHUNK (CB_N / CHUNK)

typedef __attribute__((ext_vector_type(8))) _Float16 half8;
typedef __attribute__((ext_vector_type(4))) float    f32x4;

// async 16B/lane global->LDS copy (wave-uniform contiguous; m97 pattern)
__device__ __forceinline__ void gload_lds16(const void* g, void* l) {
    __builtin_amdgcn_global_load_lds(
        (const __attribute__((address_space(1))) unsigned int*)g,
        (__attribute__((address_space(3))) unsigned int*)l,
        16, 0, 0);
}

// ---------- ws layout (byte offsets) ----------
// 0: loss_adj  4: flag_cnt  8: done_cnt
// 128:    loss_part f32[1024]
// 4224:   norms     f32[1024]
// 8320:   cbh_sw    u16[1024*64]   (fp16 hi, rotate-swizzled row segments)
// 139392: cbl_sw    u16[1024*64]   (fp16 lo, same swizzle)
// 270464: flag_q i32[FCAP]  336000: flag_m1 f32[FCAP]  401536: flag_idx i32[FCAP]

// ---------------- prep: fp16 hi/lo split, swizzled rows, norms, counters ----
__global__ void vq_prep(const float* __restrict__ cb,
                        float* __restrict__ norms,
                        unsigned short* __restrict__ cbh,
                        unsigned short* __restrict__ cbl,
                        float* __restrict__ loss_adj,
                        int* __restrict__ flag_cnt,
                        int* __restrict__ done_cnt) {
    const int tid = blockIdx.x * 256 + threadIdx.x;
    if (tid == 0) *loss_adj = 0.0f;
    if (tid == 1) *flag_cnt = 0;
    if (tid == 2) *done_cnt = 0;
    const int j  = tid >> 2;
    const int s2 = tid & 3;

    const float4* r4 = (const float4*)(cb + (size_t)j * KDIM);
    float s_norm = 0.0f;
    #pragma unroll
    for (int seg8 = 0; seg8 < 2; ++seg8) {
        const int s = s2 * 2 + seg8;
        float4 v0 = r4[s * 2 + 0];
        float4 v1 = r4[s * 2 + 1];
        float e[8] = {v0.x, v0.y, v0.z, v0.w, v1.x, v1.y, v1.z, v1.w};
        unsigned hh[4], ll[4];
        #pragma unroll
        for (int c = 0; c < 8; ++c) {
            float x = e[c];
            s_norm = fmaf(x, x, s_norm);
            union { _Float16 h; unsigned short u; } ch, cl;
            ch.h = (_Float16)x;                       // RNE fp16 hi
            cl.h = (_Float16)(x - (float)ch.h);       // RNE fp16 lo
            if ((c & 1) == 0) { hh[c >> 1] = ch.u;               ll[c >> 1] = cl.u; }
            else              { hh[c >> 1] |= ((unsigned)ch.u) << 16;
                                ll[c >> 1] |= ((unsigned)cl.u) << 16; }
        }
        const int p = (s + j) & 7;                    // bank-deconflict rotate
        *(uint4*)(cbh + (size_t)j * KDIM + p * 8) = make_uint4(hh[0], hh[1], hh[2], hh[3]);
        *(uint4*)(cbl + (size_t)j * KDIM + p * 8) = make_uint4(ll[0], ll[1], ll[2], ll[3]);
    }
    s_norm += __shfl_xor(s_norm, 1, 64);
    s_norm += __shfl_xor(s_norm, 2, 64);
    if (s2 == 0) norms[j] = s_norm;
}

// ---------------- main ------------------------------------------------------
__global__ __launch_bounds__(256, 3) void vq_main(
        const float* __restrict__ z,
        const float* __restrict__ cb,
        const unsigned short* __restrict__ cbh,
        const unsigned short* __restrict__ cbl,
        const float* __restrict__ norms,
        float* __restrict__ out,
        float* __restrict__ loss_part,
        int* __restrict__ flag_q,
        float* __restrict__ flag_m1,
        int* __restrict__ flag_idx,
        int* __restrict__ flag_cnt) {
    __shared__ float          norms_s[CB_N];             // 4 KB
    __shared__ unsigned short bh_s[2][CHUNK * KDIM];     // 2 x 8 KB (dbuf, hi)
    __shared__ unsigned short bl_s[2][CHUNK * KDIM];     // 2 x 8 KB (dbuf, lo)
    __shared__ float          zn_s[128];
    __shared__ int            idx_s[128];
    __shared__ float          wsum_s[4];

    const int tid  = threadIdx.x;
    const int w    = tid >> 6;
    const int lane = tid & 63;
    const int quad = lane >> 4;
    const int l16  = lane & 15;
    const int qb   = blockIdx.x * 128;     // block's 128 queries (same batch b)
    const int b    = qb >> 12;
    const int hw0  = qb & 4095;
    const int ch0  = blockIdx.x & (NCHUNK - 1);   // de-phase chunk start

    // ---- issue stage of chunk 0 FIRST (flies under the z-read prologue)
    {
        const char* gh = (const char*)cbh + (size_t)ch0 * (CHUNK * KDIM * 2);
        const char* gl = (const char*)cbl + (size_t)ch0 * (CHUNK * KDIM * 2);
        #pragma unroll
        for (int i = 0; i < 2; ++i) {
            const int off = (w * 2 + i) * 1024 + lane * 16;
            gload_lds16(gh + off, (char*)&bh_s[0][0] + off);
            gload_lds16(gl + off, (char*)&bl_s[0][0] + off);
        }
    }

    // ---- stage all code norms into LDS
    *(float4*)(norms_s + tid * 4) = *(const float4*)(norms + tid * 4);

    // ---- stage A-frags: wave w owns queries [32w, 32w+32); 2 tiles of 16.
    const float* zbase = z + (size_t)b * CHW + hw0 + 32 * w;
    half8 ah[2][2], al[2][2];
    float znp[2] = {0.f, 0.f};
    #pragma unroll
    for (int t = 0; t < 2; ++t)
        #pragma unroll
        for (int ks = 0; ks < 2; ++ks)
            #pragma unroll
            for (int j = 0; j < 8; ++j) {
                float v = zbase[(size_t)(ks * 32 + quad * 8 + j) * HWD + t * 16 + l16];
                znp[t] = fmaf(v, v, znp[t]);
                float s = -2.0f * v;
                _Float16 h = (_Float16)s;             // RNE fp16 hi
                ah[t][ks][j] = h;
                al[t][ks][j] = (_Float16)(s - (float)h);   // lo
            }
    #pragma unroll
    for (int t = 0; t < 2; ++t) {
        znp[t] += __shfl_xor(znp[t], 16, 64);
        znp[t] += __shfl_xor(znp[t], 32, 64);
    }
    if (lane < 16) {
        zn_s[32 * w + lane]      = znp[0];
        zn_s[32 * w + 16 + lane] = znp[1];
    }

    float m1[2][4], m2[2][4];
    int   i1[2][4];
    #pragma unroll
    for (int t = 0; t < 2; ++t)
        #pragma unroll
        for (int r = 0; r < 4; ++r) { m1[t][r] = 3.4e38f; m2[t][r] = 3.4e38f; i1[t][r] = 0; }

    // loop-invariant swizzled segment offsets (ks=0 / ks=1)
    const int p0 = ((quad + l16) & 7) * 8;
    const int p1 = ((4 + quad + l16) & 7) * 8;

    f32x4 bank[2][2];               // [tile-parity][t] -- deferred tracking
    bank[0][0] = bank[0][1] = (f32x4){0.f, 0.f, 0.f, 0.f};
    bank[1][0] = bank[1][1] = (f32x4){0.f, 0.f, 0.f, 0.f};
    int prevCode = 0;

    __syncthreads();                // chunk 0 staged + norms_s/zn_s visible
    int cur = 0;

    for (int cc = 0; cc < NCHUNK; ++cc) {
        // ---- issue next chunk's stage into the OTHER buffer (overlaps compute)
        if (cc + 1 < NCHUNK) {
            const int chn = (cc + 1 + ch0) & (NCHUNK - 1);
            const char* gh = (const char*)cbh + (size_t)chn * (CHUNK * KDIM * 2);
            const char* gl = (const char*)cbl + (size_t)chn * (CHUNK * KDIM * 2);
            #pragma unroll
            for (int i = 0; i < 2; ++i) {
                const int off = (w * 2 + i) * 1024 + lane * 16;
                gload_lds16(gh + off, (char*)&bh_s[cur ^ 1][0] + off);
                gload_lds16(gl + off, (char*)&bl_s[cur ^ 1][0] + off);
            }
        }

        const int ch = (cc + ch0) & (NCHUNK - 1);
        #pragma unroll
        for (int t8 = 0; t8 < 4; ++t8) {               // 4 x 16 = 64 codes/chunk
            const int crow = t8 * 16 + l16;            // chunk-local code row
            const float nv = norms_s[ch * CHUNK + crow];
            const half8 bh0 = *(const half8*)(&bh_s[cur][crow * KDIM + p0]);
            const half8 bh1 = *(const half8*)(&bh_s[cur][crow * KDIM + p1]);
            const half8 bl0 = *(const half8*)(&bl_s[cur][crow * KDIM + p0]);
            const half8 bl1 = *(const half8*)(&bl_s[cur][crow * KDIM + p1]);
            const int code = ch * CHUNK + crow;
            const int bk = t8 & 1, pv = bk ^ 1;

            // track the DEFERRED tile (previous t8) held in bank[pv];
            // independent of bank[bk]'s MFMAs below -> overlaps them
            if (cc + t8 > 0) {
                #pragma unroll
                for (int t = 0; t < 2; ++t)
                    #pragma unroll
                    for (int r = 0; r < 4; ++r) {
                        float d = bank[pv][t][r];
                        bool cnd = d < m1[t][r];
                        m2[t][r] = __builtin_amdgcn_fmed3f(d, m1[t][r], m2[t][r]);
                        m1[t][r] = fminf(m1[t][r], d);
                        i1[t][r] = cnd ? prevCode : i1[t][r];
                    }
            }

            // 3-term hi/lo MFMA: (ah+al)*(bh+bl) ~ ah*bh + al*bh + ah*bl
            #pragma unroll
            for (int t = 0; t < 2; ++t) {
                f32x4 acc = {nv, nv, nv, nv};
                acc = __builtin_amdgcn_mfma_f32_16x16x32_f16(ah[t][0], bh0, acc, 0, 0, 0);
                acc = __builtin_amdgcn_mfma_f32_16x16x32_f16(al[t][0], bh0, acc, 0, 0, 0);
                acc = __builtin_amdgcn_mfma_f32_16x16x32_f16(ah[t][0], bl0, acc, 0, 0, 0);
                acc = __builtin_amdgcn_mfma_f32_16x16x32_f16(ah[t][1], bh1, acc, 0, 0, 0);
                acc = __builtin_amdgcn_mfma_f32_16x16x32_f16(al[t][1], bh1, acc, 0, 0, 0);
                acc = __builtin_amdgcn_mfma_f32_16x16x32_f16(ah[t][1], bl1, acc, 0, 0, 0);
                bank[bk][t] = acc;
            }
            prevCode = code;
        }

        __syncthreads();   // implicit vmcnt(0): next buffer landed; cur reads done
        cur ^= 1;
    }
    // final deferred tile (last t8=3 wrote bank[1])
    {
        #pragma unroll
        for (int t = 0; t < 2; ++t)
            #pragma unroll
            for (int r = 0; r < 4; ++r) {
                float d = bank[1][t][r];
                bool cnd = d < m1[t][r];
                m2[t][r] = __builtin_amdgcn_fmed3f(d, m1[t][r], m2[t][r]);
                m1[t][r] = fminf(m1[t][r], d);
                i1[t][r] = cnd ? prevCode : i1[t][r];
            }
    }

    // ---- merge across 16 lanes (code residues), first-index ties
    #pragma unroll
    for (int s = 1; s < 16; s <<= 1)
        #pragma unroll
        for (int t = 0; t < 2; ++t)
            #pragma unroll
            for (int r = 0; r < 4; ++r) {
                float o1 = __shfl_xor(m1[t][r], s, 64);
                int   oi = __shfl_xor(i1[t][r], s, 64);
                float o2 = __shfl_xor(m2[t][r], s, 64);
                m2[t][r] = __builtin_amdgcn_fmed3f(m1[t][r], o1, fminf(m2[t][r], o2));
                if (o1 < m1[t][r] || (o1 == m1[t][r] && oi < i1[t][r])) {
                    m1[t][r] = o1; i1[t][r] = oi;
                }
            }

    // ---- owners (l16==0): publish idx, batched flags, loss partial
    float lsum = 0.0f;
    if (l16 == 0) {
        int nf = 0;
        #pragma unroll
        for (int t = 0; t < 2; ++t)
            #pragma unroll
            for (int r = 0; r < 4; ++r) {
                const int ql = 32 * w + t * 16 + quad * 4 + r;
                idx_s[ql] = i1[t][r];
                lsum += m1[t][r] + zn_s[ql];
                nf += (m2[t][r] - m1[t][r] < TAU) ? 1 : 0;
            }
        if (nf) {                      // ONE atomic per flagging owner thread
            int pos = atomicAdd(flag_cnt, nf);
            #pragma unroll
            for (int t = 0; t < 2; ++t)
                #pragma unroll
                for (int r = 0; r < 4; ++r)
                    if (m2[t][r] - m1[t][r] < TAU) {
                        if (pos < FCAP) {
                            flag_q[pos]   = qb + 32 * w + t * 16 + quad * 4 + r;
                            flag_m1[pos]  = m1[t][r];
                            flag_idx[pos] = i1[t][r];
                        }
                        ++pos;
                    }
        }
    }
    #pragma unroll
    for (int s = 1; s < 64; s <<= 1) lsum += __shfl_xor(lsum, s, 64);
    if (lane == 0) wsum_s[w] = lsum;
    __syncthreads();                   // idx_s + wsum_s visible

    // per-block loss partial: plain store, NO global atomic
    if (tid == 0)
        loss_part[blockIdx.x] = wsum_s[0] + wsum_s[1] + wsum_s[2] + wsum_s[3];

    // ---- epilogue: thread -> (query tid&127, channels [32*(tid>>7),+32))
    {
        const int q   = tid & 127;
        const int cs  = (tid >> 7) * 32;
        const int idx = idx_s[q];
        const float4* row = (const float4*)(cb + (size_t)idx * KDIM + cs);
        float* op = out + 1 + (size_t)b * CHW + (size_t)cs * HWD + hw0 + q;
        #pragma unroll
        for (int i4 = 0; i4 < 8; ++i4) {
            float4 v = row[i4];
            op[(size_t)(i4 * 4 + 0) * HWD] = v.x;
            op[(size_t)(i4 * 4 + 1) * HWD] = v.y;
            op[(size_t)(i4 * 4 + 2) * HWD] = v.z;
            op[(size_t)(i4 * 4 + 3) * HWD] = v.w;
        }
    }
}

// ---------------- fix: exact fp32 re-rank for flagged queries + finalize ----
// lane = (code-in-pass lane>>2, dim-segment lane&3). Each lane holds 16 z dims
// in registers; cb loads are coalesced 16B chunks; two intra-quad shuffles
// finish each distance; 64 passes x 16 codes = all 1024 codes. (R12-proven.)
__global__ __launch_bounds__(256, 1) void vq_fix(
                       const float* __restrict__ z,
                       const float* __restrict__ cb,
                       float* __restrict__ out,
                       float* __restrict__ loss_adj,
                       const float* __restrict__ loss_part,
                       const int* __restrict__ flag_q,
                       const float* __restrict__ flag_m1,
                       const int* __restrict__ flag_idx,
                       const int* __restrict__ flag_cnt,
                       int* __restrict__ done_cnt) {
    __shared__ float red_s[4];
    __shared__ int   last_s;

    const int w    = threadIdx.x >> 6;
    const int lane = threadIdx.x & 63;
    const int seg  = lane & 3;          // 16-dim segment of the query
    const int cg   = lane >> 2;         // code-in-pass 0..15
    const int gw   = blockIdx.x * 4 + w;
    const int NW   = gridDim.x * 4;

    int n = *flag_cnt;
    if (n > FCAP) n = FCAP;

    for (int f = gw; f < n; f += NW) {
        const int   q   = flag_q[f];
        const float m1o = flag_m1[f];
        const int   io  = flag_idx[f];
        const int   b   = q >> 12;
        const int   hw  = q & 4095;

        // 16 register-resident z dims per lane (segment seg)
        float zq[16];
        float zpart = 0.0f;
        #pragma unroll
        for (int i = 0; i < 16; ++i) {
            zq[i] = z[(size_t)b * CHW + (size_t)(seg * 16 + i) * HWD + hw];
            zpart = fmaf(zq[i], zq[i], zpart);
        }
        float znorm = zpart;
        znorm += __shfl_xor(znorm, 1, 64);
        znorm += __shfl_xor(znorm, 2, 64);   // full ||z||^2 in every lane

        float best = 3.4e38f; int bj = 0;
        #pragma unroll 4
        for (int p = 0; p < 64; ++p) {
            const int j = p * 16 + cg;       // 64 passes x 16 codes = 1024
            const float4* rp = (const float4*)(cb + (size_t)j * KDIM + seg * 16);
            float d = 0.0f;
            #pragma unroll
            for (int q4 = 0; q4 < 4; ++q4) {
                float4 v = rp[q4];
                float t0 = zq[q4 * 4 + 0] - v.x;
                float t1 = zq[q4 * 4 + 1] - v.y;
                float t2 = zq[q4 * 4 + 2] - v.z;
                float t3 = zq[q4 * 4 + 3] - v.w;
                d = fmaf(t0, t0, d); d = fmaf(t1, t1, d);
                d = fmaf(t2, t2, d); d = fmaf(t3, t3, d);
            }
            d += __shfl_xor(d, 1, 64);
            d += __shfl_xor(d, 2, 64);       // full distance of code j (quad)
            if (d < best) { best = d; bj = j; }  // j ascends per lane: first-min
        }
        // reduce across 16 code-groups (quad lanes identical): steps 4..32
        #pragma unroll
        for (int s = 4; s < 64; s <<= 1) {
            float ob = __shfl_xor(best, s, 64);
            int   oj = __shfl_xor(bj, s, 64);
            if (ob < best || (ob == best && oj < bj)) { best = ob; bj = oj; }
        }
        if (bj != io) {
            out[1 + (size_t)b * CHW + (size_t)lane * HWD + hw] = cb[(size_t)bj * KDIM + lane];
            if (lane == 0) atomicAdd(loss_adj, best - (m1o + znorm));
        }
    }

    __syncthreads();
    if (threadIdx.x == 0) {
        __threadfence();
        last_s = (atomicAdd(done_cnt, 1) == (int)gridDim.x - 1) ? 1 : 0;
    }
    __syncthreads();

    if (last_s) {
        // all other blocks' loss_adj atomics + vq_main partials are visible
        float s = 0.0f;
        for (int i = threadIdx.x; i < 1024; i += 256) s += loss_part[i];
        #pragma unroll
        for (int sh = 1; sh < 64; sh <<= 1) s += __shfl_xor(s, sh, 64);
        if (lane == 0) red_s[w] = s;
        __syncthreads();
        if (threadIdx.x == 0) {
            float L = red_s[0] + red_s[1] + red_s[2] + red_s[3]
                    + atomicAdd(loss_adj, 0.0f);
            out[0] = 1.25f * L / TOTALF;
        }
    }
}

extern "C" void kernel_launch(void* const* d_in, const int* in_sizes, int n_in,
                              void* d_out, int out_size, void* d_ws, size_t ws_size,
                              hipStream_t stream) {
    const float* z  = (const float*)d_in[0];
    const float* cb = (const float*)d_in[1];
    float* out      = (float*)d_out;
    char*  ws       = (char*)d_ws;

    float*          loss_adj  = (float*)(ws + 0);
    int*            flag_cnt  = (int*)(ws + 4);
    int*            done_cnt  = (int*)(ws + 8);
    float*          loss_part = (float*)(ws + 128);
    float*          norms     = (float*)(ws + 4224);
    unsigned short* cbh       = (unsigned short*)(ws + 8320);
    unsigned short* cbl       = (unsigned short*)(ws + 139392);
    int*            flag_q    = (int*)(ws + 270464);
    float*          flag_m1   = (float*)(ws + 336000);
    int*            flag_idx  = (int*)(ws + 401536);

    vq_prep<<<dim3(16), dim3(256), 0, stream>>>(cb, norms, cbh, cbl,
                                                loss_adj, flag_cnt, done_cnt);

    vq_main<<<dim3(NQ / 128), dim3(256), 0, stream>>>(z, cb, cbh, cbl, norms, out,
                                                      loss_part, flag_q, flag_m1,
                                                      flag_idx, flag_cnt);

    vq_fix<<<dim3(256), dim3(256), 0, stream>>>(z, cb, out, loss_adj, loss_part,
                                                flag_q, flag_m1, flag_idx,
                                                flag_cnt, done_cnt);
}

// Round 7
// 159.704 us; speedup vs baseline: 1.7928x; 1.0134x over previous
//
#include <hip/hip_runtime.h>

// VQ-VAE VectorQuantizer: fp16 hi/lo 3-term MFMA distance + exact fp32 fallback.
// z: (32,64,64,64) NCHW fp32; codebook: (1024,64) fp32.
// d_out: [0]=loss, [1..]=z_q (NCHW).
//
// R15 (from R14 post-mortem): R14's main regressed 61->95us: CHUNK 64 doubled
// barrier events (16/block) with half the compute to amortize each, and the
// 1024-block grid at ~3 resident/CU ran as 768+256 (tail ~ 2 rounds,
// occupancy 22% = 0.59x cap). Work itself (MFMA+VALU+LDS ~10-15us) never
// explained 95us -> per-chunk fixed overhead F dominates. This round:
//  - 256 queries/block, 512 blocks (= exactly 2/CU, single round, NO tail),
//    4 query-tiles per wave -> per-barrier compute 4x R14's.
//  - CHUNK back to 128, hi|lo COMBINED chunk-major layout
//    cbx[chunk][plane][128][64]: one staging stream, 8 gload_lds/thread/chunk,
//    8 barriers/block (was 16). B-frag ds_reads serve 2x queries.
//  - codebook L2 traffic halves (268->134 MB); 4 independent 6-MFMA chains
//    per t8 hide MFMA latency.
//  - LDS 70KB (2 blocks/CU), __launch_bounds__(256,2) caps VGPR at 256
//    (demand ~220, no spill).
// Keeps: 3-term fp16 hi/lo (error ~1e-4, TAU=1e-3 -> ~250 flags), R12-proven
// vq_fix (now sums 512 partials), batched flag atomics, per-block loss
// partials, deferred tracking banks, rotate swizzle.

#define CB_N   1024
#define KDIM   64
#define HWD    4096
#define CHW    (KDIM * HWD)
#define NQ     131072
#define TOTALF 8388608.0f
#define TAU    1.0e-3f
#define FCAP   16384
#define CHUNK  128            // codes per LDS chunk
#define NCHUNK (CB_N / CHUNK) // 8
#define PLSTR  (CHUNK * KDIM) // u16 stride between hi and lo planes (8192)
#define NBLK   512            // vq_main grid

typedef __attribute__((ext_vector_type(8))) _Float16 half8;
typedef __attribute__((ext_vector_type(4))) float    f32x4;

// async 16B/lane global->LDS copy (wave-uniform contiguous; m97 pattern)
__device__ __forceinline__ void gload_lds16(const void* g, void* l) {
    __builtin_amdgcn_global_load_lds(
        (const __attribute__((address_space(1))) unsigned int*)g,
        (__attribute__((address_space(3))) unsigned int*)l,
        16, 0, 0);
}

// ---------- ws layout (byte offsets) ----------
// 0: loss_adj  4: flag_cnt  8: done_cnt
// 128:    loss_part f32[512]
// 4224:   norms     f32[1024]
// 8320:   cbx       u16[8][2][128][64]  (fp16 hi|lo, chunk-major, rotate-swz)
// 270464: flag_q i32[FCAP]  336000: flag_m1 f32[FCAP]  401536: flag_idx i32[FCAP]

// ---------------- prep: fp16 hi/lo split, combined layout, norms ------------
__global__ void vq_prep(const float* __restrict__ cb,
                        float* __restrict__ norms,
                        unsigned short* __restrict__ cbx,
                        float* __restrict__ loss_adj,
                        int* __restrict__ flag_cnt,
                        int* __restrict__ done_cnt) {
    const int tid = blockIdx.x * 256 + threadIdx.x;
    if (tid == 0) *loss_adj = 0.0f;
    if (tid == 1) *flag_cnt = 0;
    if (tid == 2) *done_cnt = 0;
    const int j  = tid >> 2;
    const int s2 = tid & 3;

    const int chunk = j >> 7;         // code's chunk
    const int row   = j & 127;        // row within chunk
    unsigned short* hi = cbx + ((size_t)chunk * 2 + 0) * PLSTR + row * KDIM;
    unsigned short* lo = cbx + ((size_t)chunk * 2 + 1) * PLSTR + row * KDIM;

    const float4* r4 = (const float4*)(cb + (size_t)j * KDIM);
    float s_norm = 0.0f;
    #pragma unroll
    for (int seg8 = 0; seg8 < 2; ++seg8) {
        const int s = s2 * 2 + seg8;
        float4 v0 = r4[s * 2 + 0];
        float4 v1 = r4[s * 2 + 1];
        float e[8] = {v0.x, v0.y, v0.z, v0.w, v1.x, v1.y, v1.z, v1.w};
        unsigned hh[4], ll[4];
        #pragma unroll
        for (int c = 0; c < 8; ++c) {
            float x = e[c];
            s_norm = fmaf(x, x, s_norm);
            union { _Float16 h; unsigned short u; } ch, cl;
            ch.h = (_Float16)x;                       // RNE fp16 hi
            cl.h = (_Float16)(x - (float)ch.h);       // RNE fp16 lo
            if ((c & 1) == 0) { hh[c >> 1] = ch.u;               ll[c >> 1] = cl.u; }
            else              { hh[c >> 1] |= ((unsigned)ch.u) << 16;
                                ll[c >> 1] |= ((unsigned)cl.u) << 16; }
        }
        const int p = (s + j) & 7;                    // bank-deconflict rotate
        *(uint4*)(hi + p * 8) = make_uint4(hh[0], hh[1], hh[2], hh[3]);
        *(uint4*)(lo + p * 8) = make_uint4(ll[0], ll[1], ll[2], ll[3]);
    }
    s_norm += __shfl_xor(s_norm, 1, 64);
    s_norm += __shfl_xor(s_norm, 2, 64);
    if (s2 == 0) norms[j] = s_norm;
}

// ---------------- main ------------------------------------------------------
__global__ __launch_bounds__(256, 2) void vq_main(
        const float* __restrict__ z,
        const float* __restrict__ cb,
        const unsigned short* __restrict__ cbx,
        const float* __restrict__ norms,
        float* __restrict__ out,
        float* __restrict__ loss_part,
        int* __restrict__ flag_q,
        float* __restrict__ flag_m1,
        int* __restrict__ flag_idx,
        int* __restrict__ flag_cnt) {
    __shared__ float          norms_s[CB_N];             // 4 KB
    __shared__ unsigned short bx_s[2][2 * PLSTR];        // 2 x 32 KB (dbuf, hi|lo)
    __shared__ float          zn_s[256];
    __shared__ int            idx_s[256];
    __shared__ float          wsum_s[4];

    const int tid  = threadIdx.x;
    const int w    = tid >> 6;
    const int lane = tid & 63;
    const int quad = lane >> 4;
    const int l16  = lane & 15;
    const int qb   = blockIdx.x * 256;     // block's 256 queries (same batch b)
    const int b    = qb >> 12;
    const int hw0  = qb & 4095;
    const int ch0  = blockIdx.x & (NCHUNK - 1);   // de-phase chunk start

    // ---- issue stage of chunk 0 FIRST (flies under the z-read prologue)
    {
        const char* g = (const char*)cbx + (size_t)ch0 * (2 * PLSTR * 2);
        #pragma unroll
        for (int i = 0; i < 8; ++i) {
            const int off = (w * 8 + i) * 1024 + lane * 16;
            gload_lds16(g + off, (char*)&bx_s[0][0] + off);
        }
    }

    // ---- stage all code norms into LDS
    *(float4*)(norms_s + tid * 4) = *(const float4*)(norms + tid * 4);

    // ---- stage A-frags: wave w owns queries [64w, 64w+64); 4 tiles of 16.
    const float* zbase = z + (size_t)b * CHW + hw0 + 64 * w;
    half8 ah[4][2], al[4][2];
    float znp[4] = {0.f, 0.f, 0.f, 0.f};
    #pragma unroll
    for (int t = 0; t < 4; ++t)
        #pragma unroll
        for (int ks = 0; ks < 2; ++ks)
            #pragma unroll
            for (int j = 0; j < 8; ++j) {
                float v = zbase[(size_t)(ks * 32 + quad * 8 + j) * HWD + t * 16 + l16];
                znp[t] = fmaf(v, v, znp[t]);
                float s = -2.0f * v;
                _Float16 h = (_Float16)s;             // RNE fp16 hi
                ah[t][ks][j] = h;
                al[t][ks][j] = (_Float16)(s - (float)h);   // lo
            }
    #pragma unroll
    for (int t = 0; t < 4; ++t) {
        znp[t] += __shfl_xor(znp[t], 16, 64);
        znp[t] += __shfl_xor(znp[t], 32, 64);
    }
    if (lane < 16)
        #pragma unroll
        for (int t = 0; t < 4; ++t)
            zn_s[64 * w + t * 16 + lane] = znp[t];

    float m1[4][4], m2[4][4];
    int   i1[4][4];
    #pragma unroll
    for (int t = 0; t < 4; ++t)
        #pragma unroll
        for (int r = 0; r < 4; ++r) { m1[t][r] = 3.4e38f; m2[t][r] = 3.4e38f; i1[t][r] = 0; }

    // loop-invariant swizzled segment offsets (ks=0 / ks=1)
    const int p0 = ((quad + l16) & 7) * 8;
    const int p1 = ((4 + quad + l16) & 7) * 8;

    f32x4 bank[2][4];               // [tile-parity][t] -- deferred tracking
    #pragma unroll
    for (int t = 0; t < 4; ++t) {
        bank[0][t] = (f32x4){0.f, 0.f, 0.f, 0.f};
        bank[1][t] = (f32x4){0.f, 0.f, 0.f, 0.f};
    }
    int prevCode = 0;

    __syncthreads();                // chunk 0 staged + norms_s/zn_s visible
    int cur = 0;

    for (int cc = 0; cc < NCHUNK; ++cc) {
        // ---- issue next chunk's stage into the OTHER buffer (overlaps compute)
        if (cc + 1 < NCHUNK) {
            const int chn = (cc + 1 + ch0) & (NCHUNK - 1);
            const char* g = (const char*)cbx + (size_t)chn * (2 * PLSTR * 2);
            char* lh = (char*)&bx_s[cur ^ 1][0];
            #pragma unroll
            for (int i = 0; i < 8; ++i) {
                const int off = (w * 8 + i) * 1024 + lane * 16;
                gload_lds16(g + off, lh + off);
            }
        }

        const int ch = (cc + ch0) & (NCHUNK - 1);
        #pragma unroll
        for (int t8 = 0; t8 < 8; ++t8) {               // 8 x 16 = 128 codes/chunk
            const int crow = t8 * 16 + l16;            // chunk-local code row
            const float nv = norms_s[ch * CHUNK + crow];
            const half8 bh0 = *(const half8*)(&bx_s[cur][crow * KDIM + p0]);
            const half8 bh1 = *(const half8*)(&bx_s[cur][crow * KDIM + p1]);
            const half8 bl0 = *(const half8*)(&bx_s[cur][PLSTR + crow * KDIM + p0]);
            const half8 bl1 = *(const half8*)(&bx_s[cur][PLSTR + crow * KDIM + p1]);
            const int code = ch * CHUNK + crow;
            const int bk = t8 & 1, pv = bk ^ 1;

            // track the DEFERRED tile (previous t8) held in bank[pv];
            // independent of bank[bk]'s MFMAs below -> overlaps them
            if (cc + t8 > 0) {
                #pragma unroll
                for (int t = 0; t < 4; ++t)
                    #pragma unroll
                    for (int r = 0; r < 4; ++r) {
                        float d = bank[pv][t][r];
                        bool cnd = d < m1[t][r];
                        m2[t][r] = __builtin_amdgcn_fmed3f(d, m1[t][r], m2[t][r]);
                        m1[t][r] = fminf(m1[t][r], d);
                        i1[t][r] = cnd ? prevCode : i1[t][r];
                    }
            }

            // 3-term hi/lo MFMA: (ah+al)*(bh+bl) ~ ah*bh + al*bh + ah*bl
            // 4 independent 6-chains (one per tile t) -> latency hidden by ILP
            #pragma unroll
            for (int t = 0; t < 4; ++t) {
                f32x4 acc = {nv, nv, nv, nv};
                acc = __builtin_amdgcn_mfma_f32_16x16x32_f16(ah[t][0], bh0, acc, 0, 0, 0);
                acc = __builtin_amdgcn_mfma_f32_16x16x32_f16(al[t][0], bh0, acc, 0, 0, 0);
                acc = __builtin_amdgcn_mfma_f32_16x16x32_f16(ah[t][0], bl0, acc, 0, 0, 0);
                acc = __builtin_amdgcn_mfma_f32_16x16x32_f16(ah[t][1], bh1, acc, 0, 0, 0);
                acc = __builtin_amdgcn_mfma_f32_16x16x32_f16(al[t][1], bh1, acc, 0, 0, 0);
                acc = __builtin_amdgcn_mfma_f32_16x16x32_f16(ah[t][1], bl1, acc, 0, 0, 0);
                bank[bk][t] = acc;
            }
            prevCode = code;
        }

        __syncthreads();   // implicit vmcnt(0): next buffer landed; cur reads done
        cur ^= 1;
    }
    // final deferred tile (last t8=7 wrote bank[1])
    {
        #pragma unroll
        for (int t = 0; t < 4; ++t)
            #pragma unroll
            for (int r = 0; r < 4; ++r) {
                float d = bank[1][t][r];
                bool cnd = d < m1[t][r];
                m2[t][r] = __builtin_amdgcn_fmed3f(d, m1[t][r], m2[t][r]);
                m1[t][r] = fminf(m1[t][r], d);
                i1[t][r] = cnd ? prevCode : i1[t][r];
            }
    }

    // ---- merge across 16 lanes (code residues), first-index ties
    #pragma unroll
    for (int s = 1; s < 16; s <<= 1)
        #pragma unroll
        for (int t = 0; t < 4; ++t)
            #pragma unroll
            for (int r = 0; r < 4; ++r) {
                float o1 = __shfl_xor(m1[t][r], s, 64);
                int   oi = __shfl_xor(i1[t][r], s, 64);
                float o2 = __shfl_xor(m2[t][r], s, 64);
                m2[t][r] = __builtin_amdgcn_fmed3f(m1[t][r], o1, fminf(m2[t][r], o2));
                if (o1 < m1[t][r] || (o1 == m1[t][r] && oi < i1[t][r])) {
                    m1[t][r] = o1; i1[t][r] = oi;
                }
            }

    // ---- owners (l16==0): publish idx, batched flags, loss partial
    float lsum = 0.0f;
    if (l16 == 0) {
        int nf = 0;
        #pragma unroll
        for (int t = 0; t < 4; ++t)
            #pragma unroll
            for (int r = 0; r < 4; ++r) {
                const int ql = 64 * w + t * 16 + quad * 4 + r;
                idx_s[ql] = i1[t][r];
                lsum += m1[t][r] + zn_s[ql];
                nf += (m2[t][r] - m1[t][r] < TAU) ? 1 : 0;
            }
        if (nf) {                      // ONE atomic per flagging owner thread
            int pos = atomicAdd(flag_cnt, nf);
            #pragma unroll
            for (int t = 0; t < 4; ++t)
                #pragma unroll
                for (int r = 0; r < 4; ++r)
                    if (m2[t][r] - m1[t][r] < TAU) {
                        if (pos < FCAP) {
                            flag_q[pos]   = qb + 64 * w + t * 16 + quad * 4 + r;
                            flag_m1[pos]  = m1[t][r];
                            flag_idx[pos] = i1[t][r];
                        }
                        ++pos;
                    }
        }
    }
    #pragma unroll
    for (int s = 1; s < 64; s <<= 1) lsum += __shfl_xor(lsum, s, 64);
    if (lane == 0) wsum_s[w] = lsum;
    __syncthreads();                   // idx_s + wsum_s visible

    // per-block loss partial: plain store, NO global atomic
    if (tid == 0)
        loss_part[blockIdx.x] = wsum_s[0] + wsum_s[1] + wsum_s[2] + wsum_s[3];

    // ---- epilogue: thread tid -> query tid, all 64 channels (coalesced per
    //      channel across the 256 threads)
    {
        const int q   = tid;
        const int idx = idx_s[q];
        const float4* row = (const float4*)(cb + (size_t)idx * KDIM);
        float* op = out + 1 + (size_t)b * CHW + hw0 + q;
        #pragma unroll
        for (int i4 = 0; i4 < 16; ++i4) {
            float4 v = row[i4];
            op[(size_t)(i4 * 4 + 0) * HWD] = v.x;
            op[(size_t)(i4 * 4 + 1) * HWD] = v.y;
            op[(size_t)(i4 * 4 + 2) * HWD] = v.z;
            op[(size_t)(i4 * 4 + 3) * HWD] = v.w;
        }
    }
}

// ---------------- fix: exact fp32 re-rank for flagged queries + finalize ----
// lane = (code-in-pass lane>>2, dim-segment lane&3). Each lane holds 16 z dims
// in registers; cb loads are coalesced 16B chunks; two intra-quad shuffles
// finish each distance; 64 passes x 16 codes = all 1024 codes. (R12-proven.)
__global__ __launch_bounds__(256, 1) void vq_fix(
                       const float* __restrict__ z,
                       const float* __restrict__ cb,
                       float* __restrict__ out,
                       float* __restrict__ loss_adj,
                       const float* __restrict__ loss_part,
                       const int* __restrict__ flag_q,
                       const float* __restrict__ flag_m1,
                       const int* __restrict__ flag_idx,
                       const int* __restrict__ flag_cnt,
                       int* __restrict__ done_cnt) {
    __shared__ float red_s[4];
    __shared__ int   last_s;

    const int w    = threadIdx.x >> 6;
    const int lane = threadIdx.x & 63;
    const int seg  = lane & 3;          // 16-dim segment of the query
    const int cg   = lane >> 2;         // code-in-pass 0..15
    const int gw   = blockIdx.x * 4 + w;
    const int NW   = gridDim.x * 4;

    int n = *flag_cnt;
    if (n > FCAP) n = FCAP;

    for (int f = gw; f < n; f += NW) {
        const int   q   = flag_q[f];
        const float m1o = flag_m1[f];
        const int   io  = flag_idx[f];
        const int   b   = q >> 12;
        const int   hw  = q & 4095;

        // 16 register-resident z dims per lane (segment seg)
        float zq[16];
        float zpart = 0.0f;
        #pragma unroll
        for (int i = 0; i < 16; ++i) {
            zq[i] = z[(size_t)b * CHW + (size_t)(seg * 16 + i) * HWD + hw];
            zpart = fmaf(zq[i], zq[i], zpart);
        }
        float znorm = zpart;
        znorm += __shfl_xor(znorm, 1, 64);
        znorm += __shfl_xor(znorm, 2, 64);   // full ||z||^2 in every lane

        float best = 3.4e38f; int bj = 0;
        #pragma unroll 4
        for (int p = 0; p < 64; ++p) {
            const int j = p * 16 + cg;       // 64 passes x 16 codes = 1024
            const float4* rp = (const float4*)(cb + (size_t)j * KDIM + seg * 16);
            float d = 0.0f;
            #pragma unroll
            for (int q4 = 0; q4 < 4; ++q4) {
                float4 v = rp[q4];
                float t0 = zq[q4 * 4 + 0] - v.x;
                float t1 = zq[q4 * 4 + 1] - v.y;
                float t2 = zq[q4 * 4 + 2] - v.z;
                float t3 = zq[q4 * 4 + 3] - v.w;
                d = fmaf(t0, t0, d); d = fmaf(t1, t1, d);
                d = fmaf(t2, t2, d); d = fmaf(t3, t3, d);
            }
            d += __shfl_xor(d, 1, 64);
            d += __shfl_xor(d, 2, 64);       // full distance of code j (quad)
            if (d < best) { best = d; bj = j; }  // j ascends per lane: first-min
        }
        // reduce across 16 code-groups (quad lanes identical): steps 4..32
        #pragma unroll
        for (int s = 4; s < 64; s <<= 1) {
            float ob = __shfl_xor(best, s, 64);
            int   oj = __shfl_xor(bj, s, 64);
            if (ob < best || (ob == best && oj < bj)) { best = ob; bj = oj; }
        }
        if (bj != io) {
            out[1 + (size_t)b * CHW + (size_t)lane * HWD + hw] = cb[(size_t)bj * KDIM + lane];
            if (lane == 0) atomicAdd(loss_adj, best - (m1o + znorm));
        }
    }

    __syncthreads();
    if (threadIdx.x == 0) {
        __threadfence();
        last_s = (atomicAdd(done_cnt, 1) == (int)gridDim.x - 1) ? 1 : 0;
    }
    __syncthreads();

    if (last_s) {
        // all other blocks' loss_adj atomics + vq_main partials are visible
        float s = 0.0f;
        for (int i = threadIdx.x; i < NBLK; i += 256) s += loss_part[i];
        #pragma unroll
        for (int sh = 1; sh < 64; sh <<= 1) s += __shfl_xor(s, sh, 64);
        if (lane == 0) red_s[w] = s;
        __syncthreads();
        if (threadIdx.x == 0) {
            float L = red_s[0] + red_s[1] + red_s[2] + red_s[3]
                    + atomicAdd(loss_adj, 0.0f);
            out[0] = 1.25f * L / TOTALF;
        }
    }
}

extern "C" void kernel_launch(void* const* d_in, const int* in_sizes, int n_in,
                              void* d_out, int out_size, void* d_ws, size_t ws_size,
                              hipStream_t stream) {
    const float* z  = (const float*)d_in[0];
    const float* cb = (const float*)d_in[1];
    float* out      = (float*)d_out;
    char*  ws       = (char*)d_ws;

    float*          loss_adj  = (float*)(ws + 0);
    int*            flag_cnt  = (int*)(ws + 4);
    int*            done_cnt  = (int*)(ws + 8);
    float*          loss_part = (float*)(ws + 128);
    float*          norms     = (float*)(ws + 4224);
    unsigned short* cbx       = (unsigned short*)(ws + 8320);
    int*            flag_q    = (int*)(ws + 270464);
    float*          flag_m1   = (float*)(ws + 336000);
    int*            flag_idx  = (int*)(ws + 401536);

    vq_prep<<<dim3(16), dim3(256), 0, stream>>>(cb, norms, cbx,
                                                loss_adj, flag_cnt, done_cnt);

    vq_main<<<dim3(NBLK), dim3(256), 0, stream>>>(z, cb, cbx, norms, out,
                                                  loss_part, flag_q, flag_m1,
                                                  flag_idx, flag_cnt);

    vq_fix<<<dim3(256), dim3(256), 0, stream>>>(z, cb, out, loss_adj, loss_part,
                                                flag_q, flag_m1, flag_idx,
                                                flag_cnt, done_cnt);
}